// Round 1
// baseline (2623.427 us; speedup 1.0000x reference)
//
#include <hip/hip_runtime.h>
#include <cstddef>

// Problem constants (SpatialConv, KERNEL_TYPE=0: plus-shaped 5-tap conv)
#define N_   16
#define CI   256
#define H_   64
#define W_   64
#define CO   256
#define KT   5

#define CC   8      // channels staged per chunk
#define XW   66     // LDS x row width: 64 + 2 halo (always-zero at image edge)

// Prepass: weight [Co][Ci][5] -> wt [Ci][5][Co] so main-kernel staging is a
// contiguous memcpy. ck = c*5+k, so wt[ck*CO + o] = w[o*1280 + ck].
__global__ void wtrans_kernel(const float* __restrict__ w, float* __restrict__ wt) {
    int idx = blockIdx.x * 256 + threadIdx.x;   // over CI*KT*CO = 327680
    if (idx >= CI * KT * CO) return;
    int o  = idx % CO;
    int ck = idx / CO;
    wt[idx] = w[(size_t)o * (CI * KT) + ck];
}

// Block = one (n, h) row: 64 pixels x 256 output channels.
// Thread: wq = tid&15 -> pixels w = wq*4..wq*4+3 ; og = tid>>4 -> o = og*16..+15.
// 64 fp32 accumulators per thread.
__global__ __launch_bounds__(256, 3) void conv_main(
    const float* __restrict__ x, const float* __restrict__ wt,
    float* __restrict__ out)
{
    __shared__ float lx[CC][3][XW];     // 6336 B
    __shared__ float lw[CC][KT][CO];    // 40960 B

    const int tid   = threadIdx.x;
    const int n     = blockIdx.x >> 6;
    const int h     = blockIdx.x & 63;
    const int wq    = tid & 15;
    const int og    = tid >> 4;
    const int wbase = wq * 4;
    const int obase = og * 16;

    float acc[4][16];
    #pragma unroll
    for (int p = 0; p < 4; ++p)
        #pragma unroll
        for (int i = 0; i < 16; ++i) acc[p][i] = 0.f;

    const float* xn = x + (size_t)n * CI * H_ * W_;

    for (int c0 = 0; c0 < CI; c0 += CC) {
        __syncthreads();   // protect LDS from previous iteration's readers

        // ---- stage x: CC channels x 3 rows (h-1,h,h+1) x 66 (halo zeros) ----
        for (int idx = tid; idx < CC * 3 * XW; idx += 256) {
            int c   = idx / (3 * XW);
            int rem = idx - c * (3 * XW);
            int r   = rem / XW;
            int wi  = rem - r * XW;
            int hh  = h + r - 1;
            int ww  = wi - 1;
            float v = 0.f;
            if ((unsigned)hh < 64u && (unsigned)ww < 64u)
                v = xn[(((size_t)(c0 + c)) * 64 + hh) * 64 + ww];
            lx[c][r][wi] = v;
        }

        // ---- stage weights: contiguous copy of wt[c0*5*CO .. +CC*5*CO) ----
        {
            const float4* src = (const float4*)(wt + (size_t)c0 * KT * CO);
            float4* dst = (float4*)(&lw[0][0][0]);
            #pragma unroll
            for (int idx = tid; idx < CC * KT * CO / 4; idx += 256)
                dst[idx] = src[idx];
        }
        __syncthreads();

        #pragma unroll
        for (int cc = 0; cc < CC; ++cc) {
            // x registers for this thread's 4 pixels
            float xc[6];                        // center row, w-1 .. w+4
            #pragma unroll
            for (int j = 0; j < 6; ++j) xc[j] = lx[cc][1][wbase + j];
            float xu[4], xd[4];
            #pragma unroll
            for (int j = 0; j < 4; ++j) {
                xu[j] = lx[cc][0][wbase + 1 + j];
                xd[j] = lx[cc][2][wbase + 1 + j];
            }

            #pragma unroll
            for (int k = 0; k < KT; ++k) {
                const float* wp = &lw[cc][k][obase];
                float wv[16];
                #pragma unroll
                for (int i = 0; i < 16; ++i) wv[i] = wp[i];  // -> 4x ds_read_b128 (broadcast)

                // tap k -> per-pixel x value
                // k=0:(0,0)  k=1:(-1,0)  k=2:(0,-1)  k=3:(0,+1)  k=4:(+1,0)
                float xs[4];
                #pragma unroll
                for (int p = 0; p < 4; ++p) {
                    xs[p] = (k == 0) ? xc[p + 1]
                          : (k == 1) ? xu[p]
                          : (k == 2) ? xc[p]
                          : (k == 3) ? xc[p + 2]
                          :            xd[p];
                }

                #pragma unroll
                for (int p = 0; p < 4; ++p)
                    #pragma unroll
                    for (int i = 0; i < 16; ++i)
                        acc[p][i] = fmaf(xs[p], wv[i], acc[p][i]);
            }
        }
    }

    // ---- epilogue: out[n][o][h][w], coalesced float4 per (o, 4-pixel group) ----
    float* op = out + ((size_t)n * CO * 64 + h) * 64;
    #pragma unroll
    for (int i = 0; i < 16; ++i) {
        float4 v = make_float4(acc[0][i], acc[1][i], acc[2][i], acc[3][i]);
        *(float4*)(op + (size_t)(obase + i) * 4096 + wbase) = v;
    }
}

extern "C" void kernel_launch(void* const* d_in, const int* in_sizes, int n_in,
                              void* d_out, int out_size, void* d_ws, size_t ws_size,
                              hipStream_t stream) {
    const float* x = (const float*)d_in[0];
    const float* w = (const float*)d_in[1];
    // d_in[2] = step (unused)
    float* out = (float*)d_out;
    float* wt  = (float*)d_ws;   // needs CI*KT*CO*4 = 1.31 MB of workspace

    wtrans_kernel<<<dim3((CI * KT * CO + 255) / 256), dim3(256), 0, stream>>>(w, wt);
    conv_main<<<dim3(N_ * H_), dim3(256), 0, stream>>>(x, wt, out);
}

// Round 2
// 227.454 us; speedup vs baseline: 11.5339x; 11.5339x over previous
//
#include <hip/hip_runtime.h>
#include <cstddef>

// SpatialConv KERNEL_TYPE=0: 5-tap plus conv, N=16 Ci=Co=256 H=W=64, fp32 I/O.
// Strategy: bf16 MFMA GEMM. out[o,p] = sum_k sum_c wb[k][o][c] * xshift_k[c][p].
#define N_  16
#define CI  256
#define H_  64
#define W_  64
#define CO  256
#define KT  5

typedef __attribute__((ext_vector_type(8))) short  short8;   // 8 bf16 = 4 VGPRs
typedef __attribute__((ext_vector_type(8))) unsigned short ushort8;
typedef __attribute__((ext_vector_type(4))) float  floatx4;

static __device__ __forceinline__ unsigned short f2bf(float f) {
    union { float f; unsigned u; } v; v.f = f;
    unsigned r = v.u + 0x7fff + ((v.u >> 16) & 1);   // RNE
    return (unsigned short)(r >> 16);
}

// ---- prepass 1: w fp32 [Co][Ci][5] -> wb bf16 [5][Co][Ci] (c contiguous) ----
__global__ void wtrans_kernel(const float* __restrict__ w, unsigned short* __restrict__ wb) {
    int idx = blockIdx.x * 256 + threadIdx.x;       // over 5*256*256 = 327680
    if (idx >= KT * CO * CI) return;
    int k = idx >> 16;            // / 65536
    int rem = idx & 65535;
    int o = rem >> 8;
    int c = rem & 255;
    wb[idx] = f2bf(w[(size_t)o * (CI * KT) + c * KT + k]);
}

// ---- prepass 2: x fp32 [N][Ci][H][W] -> xb bf16 [N][H][W][Ci] (c contiguous) ----
__global__ __launch_bounds__(256) void xtrans_kernel(const float* __restrict__ x,
                                                     unsigned short* __restrict__ xb) {
    __shared__ unsigned short lt[64][66];            // [w][ci], pitch 66 kills conflicts
    const int tid = threadIdx.x;
    const int h = blockIdx.x & 63;
    const int n = blockIdx.x >> 6;

    for (int c0 = 0; c0 < CI; c0 += 64) {
        __syncthreads();
        // load: coalesced along w, transpose into LDS
        for (int idx = tid; idx < 64 * 64; idx += 256) {
            int ci = idx >> 6, w = idx & 63;
            float v = x[(((size_t)n * CI + c0 + ci) * 64 + h) * 64 + w];
            lt[w][ci] = f2bf(v);
        }
        __syncthreads();
        // store: c contiguous, 16B per thread
        for (int idx = tid; idx < 64 * 8; idx += 256) {   // 64 w x 8 groups of 8 c
            int g = idx & 7, w = idx >> 3;
            ushort8 v;
            #pragma unroll
            for (int e = 0; e < 8; ++e) v[e] = lt[w][g * 8 + e];
            *(ushort8*)(xb + (((size_t)(n * 64 + h) * 64 + w) * 256 + c0 + g * 8)) = v;
        }
    }
}

// ---- main: block = (o-half 128) x (n,h) row of 64 pixels; 4 waves of 32o x 64px ----
// A-frags from global wb (L2-resident). B staged in LDS with halo zeros.
__global__ __launch_bounds__(256) void conv_mfma(const unsigned short* __restrict__ xb,
                                                 const unsigned short* __restrict__ wb,
                                                 float* __restrict__ out) {
    __shared__ unsigned short lb[3 * 66 * 32];   // [r][wi][c32], 12672 B

    const int tid   = threadIdx.x;
    const int bx    = blockIdx.x;
    const int ohalf = bx & 1;
    const int h     = (bx >> 1) & 63;
    const int n     = bx >> 7;
    const int lane  = tid & 63;
    const int wv    = tid >> 6;
    const int l15   = lane & 15;
    const int quad  = lane >> 4;
    const int owave = ohalf * 128 + wv * 32;     // this wave's o-base (32 wide)

    // taps: k0=(0,0) k1=(-1,0) k2=(0,-1) k3=(0,+1) k4=(+1,0)
    // lb row r holds image row h+r-1; B for tap k at pixel w reads lb[rk][w+dxk]
    const int rk[KT]  = {1, 0, 1, 1, 2};
    const int dxk[KT] = {1, 1, 0, 2, 1};

    floatx4 acc[2][4];
    #pragma unroll
    for (int oi = 0; oi < 2; ++oi)
        #pragma unroll
        for (int j = 0; j < 4; ++j) acc[oi][j] = (floatx4){0.f, 0.f, 0.f, 0.f};

    for (int c0 = 0; c0 < CI; c0 += 32) {
        __syncthreads();
        // stage x: 3 rows x 66 wi x 32 c (bf16), halo -> 0. 198 pos x 4 x 16B.
        for (int idx = tid; idx < 198 * 4; idx += 256) {
            int part = idx & 3;
            int pos  = idx >> 2;
            int r    = pos / 66;
            int wi   = pos - r * 66;
            int hh   = h + r - 1;
            int wim  = wi - 1;
            ushort8 v = (ushort8)0;
            if ((unsigned)hh < 64u && (unsigned)wim < 64u)
                v = *(const ushort8*)(xb + (((size_t)(n * 64 + hh) * 64 + wim) * 256 + c0 + part * 8));
            *(ushort8*)(lb + pos * 32 + part * 8) = v;
        }
        __syncthreads();

        #pragma unroll
        for (int k = 0; k < KT; ++k) {
            // A-frags: lane holds o = owave + oi*16 + l15, c = c0 + quad*8 + 0..7
            const short8 a0 = *(const short8*)(wb + ((size_t)k * (CO * CI) + (owave + l15) * 256 + c0 + quad * 8));
            const short8 a1 = *(const short8*)(wb + ((size_t)k * (CO * CI) + (owave + 16 + l15) * 256 + c0 + quad * 8));
            #pragma unroll
            for (int j = 0; j < 4; ++j) {
                // B-frag: lane holds pixel n-idx = l15, k-dim = quad*8 + 0..7
                int wi = j * 16 + l15 + dxk[k];
                const short8 b = *(const short8*)(lb + ((rk[k] * 66 + wi) * 32 + quad * 8));
                acc[0][j] = __builtin_amdgcn_mfma_f32_16x16x32_bf16(a0, b, acc[0][j], 0, 0, 0);
                acc[1][j] = __builtin_amdgcn_mfma_f32_16x16x32_bf16(a1, b, acc[1][j], 0, 0, 0);
            }
        }
    }

    // epilogue: D col = pixel = l15, row = o-offset = quad*4 + reg
    #pragma unroll
    for (int oi = 0; oi < 2; ++oi) {
        #pragma unroll
        for (int reg = 0; reg < 4; ++reg) {
            int o = owave + oi * 16 + quad * 4 + reg;
            float* op = out + (((size_t)n * CO + o) * 64 + h) * 64;
            #pragma unroll
            for (int j = 0; j < 4; ++j)
                op[j * 16 + l15] = acc[oi][j][reg];
        }
    }
}

extern "C" void kernel_launch(void* const* d_in, const int* in_sizes, int n_in,
                              void* d_out, int out_size, void* d_ws, size_t ws_size,
                              hipStream_t stream) {
    const float* x = (const float*)d_in[0];
    const float* w = (const float*)d_in[1];
    float* out = (float*)d_out;

    // workspace: wb bf16 (655360 B) then xb bf16 (33554432 B) = 34.2 MB
    unsigned short* wb = (unsigned short*)d_ws;
    unsigned short* xb = (unsigned short*)((char*)d_ws + (size_t)KT * CO * CI * 2);

    wtrans_kernel<<<dim3((KT * CO * CI + 255) / 256), dim3(256), 0, stream>>>(w, wb);
    xtrans_kernel<<<dim3(N_ * H_), dim3(256), 0, stream>>>(x, xb);
    conv_mfma<<<dim3(N_ * H_ * 2), dim3(256), 0, stream>>>(xb, wb, out);
}

// Round 3
// 181.560 us; speedup vs baseline: 14.4494x; 1.2528x over previous
//
#include <hip/hip_runtime.h>
#include <cstddef>

// SpatialConv KERNEL_TYPE=0: 5-tap plus conv, N=16 Ci=Co=256 H=W=64, fp32 I/O.
// bf16 MFMA GEMM: out[o,p] = sum_k sum_c wb[k][o][c] * xshift_k[c][p].
#define N_  16
#define CI  256
#define H_  64
#define W_  64
#define CO  256
#define KT  5

#define PITCH 40   // shorts per (r,wi) LDS cell: 32 data + 8 pad (80B, 16B-aligned)

typedef __attribute__((ext_vector_type(8))) short  short8;
typedef __attribute__((ext_vector_type(8))) unsigned short ushort8;
typedef __attribute__((ext_vector_type(4))) float  floatx4;

static __device__ __forceinline__ unsigned short f2bf(float f) {
    union { float f; unsigned u; } v; v.f = f;
    unsigned r = v.u + 0x7fff + ((v.u >> 16) & 1);   // RNE
    return (unsigned short)(r >> 16);
}

// ---- prepass 1: w fp32 [Co][Ci][5] -> wb bf16 [5][Co][Ci] (c contiguous) ----
__global__ void wtrans_kernel(const float* __restrict__ w, unsigned short* __restrict__ wb) {
    int idx = blockIdx.x * 256 + threadIdx.x;       // over 5*256*256
    if (idx >= KT * CO * CI) return;
    int k = idx >> 16;
    int rem = idx & 65535;
    int o = rem >> 8;
    int c = rem & 255;
    wb[idx] = f2bf(w[(size_t)o * (CI * KT) + c * KT + k]);
}

// ---- prepass 2: x fp32 NCHW -> xb bf16 [N][c/8][H][W][8c]. No LDS/barriers.
__global__ __launch_bounds__(256) void xtrans_kernel(const float* __restrict__ x,
                                                     unsigned short* __restrict__ xb) {
    int idx = blockIdx.x * 256 + threadIdx.x;       // over 16*32*64*64 = 2097152
    int w  = idx & 63;
    int h  = (idx >> 6) & 63;
    int cg = (idx >> 12) & 31;
    int n  = idx >> 17;
    const float* xp = x + (((size_t)n * CI + cg * 8) * 64 + h) * 64 + w;
    ushort8 v;
    #pragma unroll
    for (int e = 0; e < 8; ++e) v[e] = f2bf(xp[(size_t)e * 4096]);
    *(ushort8*)(xb + (size_t)idx * 8) = v;
}

// ---- main: block = 128 o x 256 px (4 h-rows x 64 w); 4 waves = 32 o each ----
__global__ __launch_bounds__(256, 2) void conv_mfma(const unsigned short* __restrict__ xb,
                                                    const unsigned short* __restrict__ wb,
                                                    float* __restrict__ out) {
    __shared__ unsigned short lb[6 * 66 * PITCH];   // 6 rows x 66 wi x 40 shorts = 31680 B

    const int tid   = threadIdx.x;
    const int bx    = blockIdx.x;
    const int ohalf = bx & 1;
    const int hq    = (bx >> 1) & 15;     // h0 = hq*4
    const int n     = bx >> 5;
    const int h0    = hq * 4;
    const int lane  = tid & 63;
    const int wv    = tid >> 6;
    const int l15   = lane & 15;
    const int quad  = lane >> 4;
    const int owave = ohalf * 128 + wv * 32;

    // taps (dy,dx): k0=(1,1) k1=(0,1) k2=(1,0) k3=(1,2) k4=(2,1)
    const int rk[KT]  = {1, 0, 1, 1, 2};   // dy: lds r = hr + dy
    const int dxk[KT] = {1, 1, 0, 2, 1};   // dx: wi = wg*16 + l15 + dx

    floatx4 acc[2][16];
    #pragma unroll
    for (int oi = 0; oi < 2; ++oi)
        #pragma unroll
        for (int j = 0; j < 16; ++j) acc[oi][j] = (floatx4){0.f, 0.f, 0.f, 0.f};

    for (int c0 = 0; c0 < CI; c0 += 32) {
        const int c0g = c0 >> 3;
        __syncthreads();
        // stage: 6 rows (h0-1..h0+4) x 66 wi x 32 c, halo zeros.
        // idx: part slow (4 c-groups of 8), pos fast (coalesced along wi).
        for (int idx = tid; idx < 6 * 66 * 4; idx += 256) {
            int part = idx / 396;
            int pos  = idx - part * 396;
            int r    = pos / 66;
            int wi   = pos - r * 66;
            int hh   = h0 + r - 1;
            int wim  = wi - 1;
            ushort8 v = (ushort8)0;
            if ((unsigned)hh < 64u && (unsigned)wim < 64u)
                v = *(const ushort8*)(xb + (((size_t)(n * 32 + c0g + part) * 64 + hh) * 64 + wim) * 8);
            *(ushort8*)(lb + (r * 66 + wi) * PITCH + part * 8) = v;
        }
        __syncthreads();

        #pragma unroll
        for (int k = 0; k < KT; ++k) {
            const short8 a0 = *(const short8*)(wb + ((size_t)k * (CO * CI) + (owave + l15) * CI + c0 + quad * 8));
            const short8 a1 = *(const short8*)(wb + ((size_t)k * (CO * CI) + (owave + 16 + l15) * CI + c0 + quad * 8));
            #pragma unroll
            for (int j = 0; j < 16; ++j) {
                int hr = j >> 2, wg = j & 3;
                int wi = wg * 16 + l15 + dxk[k];
                const short8 b = *(const short8*)(lb + (((hr + rk[k]) * 66 + wi) * PITCH + quad * 8));
                acc[0][j] = __builtin_amdgcn_mfma_f32_16x16x32_bf16(a0, b, acc[0][j], 0, 0, 0);
                acc[1][j] = __builtin_amdgcn_mfma_f32_16x16x32_bf16(a1, b, acc[1][j], 0, 0, 0);
            }
        }
    }

    // epilogue: D col = pixel-in-group = l15, row = o-offset = quad*4 + reg
    #pragma unroll
    for (int oi = 0; oi < 2; ++oi) {
        #pragma unroll
        for (int reg = 0; reg < 4; ++reg) {
            int o = owave + oi * 16 + quad * 4 + reg;
            #pragma unroll
            for (int j = 0; j < 16; ++j) {
                int hr = j >> 2, wg = j & 3;
                out[(((size_t)n * CO + o) * 64 + (h0 + hr)) * 64 + wg * 16 + l15] = acc[oi][j][reg];
            }
        }
    }
}

extern "C" void kernel_launch(void* const* d_in, const int* in_sizes, int n_in,
                              void* d_out, int out_size, void* d_ws, size_t ws_size,
                              hipStream_t stream) {
    const float* x = (const float*)d_in[0];
    const float* w = (const float*)d_in[1];
    float* out = (float*)d_out;

    unsigned short* wb = (unsigned short*)d_ws;                                   // 655360 B
    unsigned short* xb = (unsigned short*)((char*)d_ws + (size_t)KT * CO * CI * 2); // 33.5 MB

    wtrans_kernel<<<dim3((KT * CO * CI + 255) / 256), dim3(256), 0, stream>>>(w, wb);
    xtrans_kernel<<<dim3(16 * 32 * 64 * 64 / 256), dim3(256), 0, stream>>>(x, xb);
    conv_mfma<<<dim3(N_ * (H_ / 4) * 2), dim3(256), 0, stream>>>(xb, wb, out);
}

// Round 4
// 162.349 us; speedup vs baseline: 16.1592x; 1.1183x over previous
//
#include <hip/hip_runtime.h>
#include <cstddef>
#include <cstdint>

// SpatialConv KERNEL_TYPE=0: 5-tap plus conv, N=16 Ci=Co=256 H=W=64, fp32 I/O.
// bf16 MFMA GEMM with async global_load_lds double-buffered K-loop
// (vmcnt held >0 across barriers, AITER-style).
#define N_  16
#define CI  256
#define H_  64
#define W_  64
#define CO  256
#define KT  5

typedef __attribute__((ext_vector_type(8))) short  short8;
typedef __attribute__((ext_vector_type(8))) unsigned short ushort8;
typedef __attribute__((ext_vector_type(4))) float  floatx4;

typedef const __attribute__((address_space(1))) unsigned int gas_uint;
typedef __attribute__((address_space(3))) unsigned int las_uint;

static __device__ __forceinline__ unsigned short f2bf(float f) {
    union { float f; unsigned u; } v; v.f = f;
    unsigned r = v.u + 0x7fff + ((v.u >> 16) & 1);   // RNE
    return (unsigned short)(r >> 16);
}

// ---- prepass 1: w fp32 [Co][Ci][5] -> wb bf16 [5][Co][Ci] (c contiguous) ----
__global__ void wtrans_kernel(const float* __restrict__ w, unsigned short* __restrict__ wb) {
    int idx = blockIdx.x * 256 + threadIdx.x;
    if (idx >= KT * CO * CI) return;
    int k = idx >> 16;
    int rem = idx & 65535;
    int o = rem >> 8;
    int c = rem & 255;
    wb[idx] = f2bf(w[(size_t)o * (CI * KT) + c * KT + k]);
}

// ---- prepass 2: x fp32 NCHW -> xb bf16 [N][c/8][H][W][8c]. No LDS/barriers.
__global__ __launch_bounds__(256) void xtrans_kernel(const float* __restrict__ x,
                                                     unsigned short* __restrict__ xb) {
    int idx = blockIdx.x * 256 + threadIdx.x;       // over 16*32*64*64 = 2097152
    int w  = idx & 63;
    int h  = (idx >> 6) & 63;
    int cg = (idx >> 12) & 31;
    int n  = idx >> 17;
    const float* xp = x + (((size_t)n * CI + cg * 8) * 64 + h) * 64 + w;
    ushort8 v;
    #pragma unroll
    for (int e = 0; e < 8; ++e) v[e] = f2bf(xp[(size_t)e * 4096]);
    *(ushort8*)(xb + (size_t)idx * 8) = v;
}

// ---- main: block = 128 o x 256 px (4 h-rows x 64 w); 4 waves = 32 o each ----
// LDS buffer layout: slot(r, part, w) = r*256 + part*64 + w, 16B/slot.
//   r = 0..5 -> image row h0+r-1 ; part = c-group-of-8 within chunk ; w = image col.
// Halo: w=-1 / w=64 reads -> shared zero cell; OOB rows pre-zeroed, not staged.
__global__ __launch_bounds__(256, 2) void conv_mfma(const unsigned short* __restrict__ xb,
                                                    const unsigned short* __restrict__ wb,
                                                    float* __restrict__ out) {
    __shared__ ushort8 lds[2 * 1536 + 1];   // 2 x 24576 B + 16 B zero cell

    const int tid   = threadIdx.x;
    const int bx    = blockIdx.x;
    const int ohalf = bx & 1;
    const int hq    = (bx >> 1) & 15;
    const int n     = bx >> 5;
    const int h0    = hq * 4;
    const int lane  = tid & 63;
    const int wv    = tid >> 6;          // wave id = staging c-group ("part")
    const int l15   = lane & 15;
    const int quad  = lane >> 4;
    const int owave = ohalf * 128 + wv * 32;

    const int rlo = (h0 == 0)  ? 1 : 0;
    const int rhi = (h0 == 60) ? 4 : 5;
    const bool full = (rlo == 0) && (rhi == 5);   // nstage = 6 else 5

    // prologue: zero cell + never-staged edge rows (both buffers)
    if (tid == 0) lds[2 * 1536] = (ushort8)0;
    if (h0 == 0) {
        lds[0 * 1536 + 0 * 256 + tid] = (ushort8)0;
        lds[1 * 1536 + 0 * 256 + tid] = (ushort8)0;
    }
    if (h0 == 60) {
        lds[0 * 1536 + 5 * 256 + tid] = (ushort8)0;
        lds[1 * 1536 + 5 * 256 + tid] = (ushort8)0;
    }
    __syncthreads();

    // per-thread staging base (chunk 0, r 0): xb index in shorts
    const unsigned short* gbase =
        xb + (((size_t)(n * 32 + wv) * 64 + (h0 - 1)) * 64 + lane) * 8;
    // chunk step: 4 c-groups * 4096 px * 8 = 131072 shorts; row step: 64*8 = 512

    // A-frag base: wb[k][owave + oi*16 + l15][c0 + quad*8 ...]
    const unsigned short* wbase = wb + ((size_t)(owave + l15)) * 256 + quad * 8;

    floatx4 acc[2][16];
    #pragma unroll
    for (int oi = 0; oi < 2; ++oi)
        #pragma unroll
        for (int j = 0; j < 16; ++j) acc[oi][j] = (floatx4){0.f, 0.f, 0.f, 0.f};

    // ---- issue staging for chunk ch into buffer b (one 16B DMA per row) ----
    auto stage = [&](int ch, int b) {
        const unsigned short* g = gbase + (size_t)ch * 131072;
        for (int r = rlo; r <= rhi; ++r) {
            __builtin_amdgcn_global_load_lds(
                (gas_uint*)(g + r * 512),
                (las_uint*)&lds[b * 1536 + r * 256 + tid],
                16, 0, 0);
        }
    };

    stage(0, 0);

    for (int c = 0; c < 8; ++c) {
        const int cb = c & 1;
        const int c0 = c * 32;

        // A-frags for chunk c (10 x 16B, L2-resident wb)
        short8 a[2][KT];
        #pragma unroll
        for (int k = 0; k < KT; ++k) {
            a[0][k] = *(const short8*)(wbase + (size_t)k * 65536 + c0);
            a[1][k] = *(const short8*)(wbase + (size_t)k * 65536 + 4096 + c0);
        }

        // prefetch chunk c+1 into the other buffer
        if (c < 7) stage(c + 1, cb ^ 1);

        // wait until chunk-c staging (the oldest vmem ops) has landed, keeping
        // chunk-(c+1)'s loads in flight. lgkmcnt/expcnt unconstrained (0xF7_).
        if (c < 7) {
            if (full) __builtin_amdgcn_s_waitcnt(0x0F76);   // vmcnt(6)
            else      __builtin_amdgcn_s_waitcnt(0x0F75);   // vmcnt(5)
        } else {
            __builtin_amdgcn_s_waitcnt(0x0F70);             // vmcnt(0)
        }
        __builtin_amdgcn_s_barrier();                        // [A] chunk c visible

        const ushort8* buf = &lds[cb * 1536];
        // taps (dy,dx): k0=(1,1) k1=(0,1) k2=(1,0) k3=(1,2) k4=(2,1)
        #pragma unroll
        for (int k = 0; k < KT; ++k) {
            const int dy  = (k == 1) ? 0 : (k == 4) ? 2 : 1;
            const int dx  = (k == 2) ? 0 : (k == 3) ? 2 : 1;
            #pragma unroll
            for (int j = 0; j < 16; ++j) {
                const int hr = j >> 2, wg = j & 3;
                const int r  = hr + dy;
                const int xw = wg * 16 + l15 + dx - 1;
                const ushort8* bp = ((unsigned)xw < 64u)
                    ? &buf[r * 256 + quad * 64 + xw]
                    : &lds[2 * 1536];                       // zero cell (broadcast)
                const short8 bfrag = *(const short8*)bp;
                acc[0][j] = __builtin_amdgcn_mfma_f32_16x16x32_bf16(a[0][k], bfrag, acc[0][j], 0, 0, 0);
                acc[1][j] = __builtin_amdgcn_mfma_f32_16x16x32_bf16(a[1][k], bfrag, acc[1][j], 0, 0, 0);
            }
        }
        __builtin_amdgcn_s_barrier();                        // [B] buf[cb] free
    }

    // epilogue: D col = pixel-in-group = l15, row = o-offset = quad*4 + reg
    #pragma unroll
    for (int oi = 0; oi < 2; ++oi) {
        #pragma unroll
        for (int reg = 0; reg < 4; ++reg) {
            int o = owave + oi * 16 + quad * 4 + reg;
            #pragma unroll
            for (int j = 0; j < 16; ++j) {
                int hr = j >> 2, wg = j & 3;
                out[(((size_t)n * CO + o) * 64 + (h0 + hr)) * 64 + wg * 16 + l15] = acc[oi][j][reg];
            }
        }
    }
}

extern "C" void kernel_launch(void* const* d_in, const int* in_sizes, int n_in,
                              void* d_out, int out_size, void* d_ws, size_t ws_size,
                              hipStream_t stream) {
    const float* x = (const float*)d_in[0];
    const float* w = (const float*)d_in[1];
    float* out = (float*)d_out;

    unsigned short* wb = (unsigned short*)d_ws;                                     // 655360 B
    unsigned short* xb = (unsigned short*)((char*)d_ws + (size_t)KT * CO * CI * 2); // 33.5 MB

    wtrans_kernel<<<dim3((KT * CO * CI + 255) / 256), dim3(256), 0, stream>>>(w, wb);
    xtrans_kernel<<<dim3(16 * 32 * 64 * 64 / 256), dim3(256), 0, stream>>>(x, xb);
    conv_mfma<<<dim3(N_ * (H_ / 4) * 2), dim3(256), 0, stream>>>(xb, wb, out);
}

// Round 5
// 159.215 us; speedup vs baseline: 16.4773x; 1.0197x over previous
//
#include <hip/hip_runtime.h>
#include <hip/hip_bf16.h>
#include <cstddef>

// SpatialConv KERNEL_TYPE=0: 5-tap plus conv, N=16 Ci=Co=256 H=W=64, fp32 I/O.
// 32x32x16 bf16 MFMA; x staged fp32->bf16 in-kernel (no xb workspace/prepass).
#define N_  16
#define CI  256
#define CO  256
#define KT  5

typedef __attribute__((ext_vector_type(8)))  short  short8;
typedef __attribute__((ext_vector_type(8)))  unsigned short ushort8;
typedef __attribute__((ext_vector_type(4)))  unsigned int uint4v;
typedef __attribute__((ext_vector_type(16))) float  floatx16;

static __device__ __forceinline__ unsigned short f2bf(float f) {
    union { float f; unsigned u; } v; v.f = f;
    unsigned r = v.u + 0x7fff + ((v.u >> 16) & 1);   // RNE
    return (unsigned short)(r >> 16);
}

// ---- prepass: w fp32 [Co][Ci][5] -> wb bf16 [5][Co][Ci] (c contiguous) ----
__global__ void wtrans_kernel(const float* __restrict__ w, unsigned short* __restrict__ wb) {
    int idx = blockIdx.x * 256 + threadIdx.x;
    if (idx >= KT * CO * CI) return;
    int k = idx >> 16;
    int rem = idx & 65535;
    int o = rem >> 8;
    int c = rem & 255;
    wb[idx] = f2bf(w[(size_t)o * (CI * KT) + c * KT + k]);
}

// ---- main: block = 128 o x 256 px (4 h-rows x 64 w); wave = 64 o x 128 px ----
// LDS cell(r, cg, w) = 16B of 8 bf16 channels; slot = r*256 + cg*64 + w.
//   r = 0..5 -> image row h0+r-1 ; cg = chunk-c/8 ; w = image col.
__global__ __launch_bounds__(256, 2) void conv_mfma(const float* __restrict__ x,
                                                    const unsigned short* __restrict__ wb,
                                                    float* __restrict__ out) {
    __shared__ ushort8 lds[2 * 1536 + 1];   // 2 x 24 KB + zero cell

    const int tid   = threadIdx.x;
    const int bx    = blockIdx.x;
    const int ohalf = bx & 1;
    const int hq    = (bx >> 1) & 15;
    const int n     = bx >> 5;
    const int h0    = hq * 4;
    const int lane  = tid & 63;
    const int wv    = tid >> 6;
    const int l31   = lane & 31;
    const int lh    = lane >> 5;
    const int owave   = ohalf * 128 + (wv & 1) * 64;   // wave o-base (64 wide)
    const int rowbase = (wv >> 1) * 2;                 // wave h-rows: rowbase, rowbase+1

    // staging: thread owns cells (r=i, scg, sw), i = 0..5
    const int sw  = tid & 63;
    const int scg = (tid >> 6) & 3;

    if (tid == 0) lds[2 * 1536] = (ushort8)0;

    const float* xn = x + (size_t)n * CI * 4096;

    float xr[6][8];
    auto load_chunk = [&](int c) {
        #pragma unroll
        for (int i = 0; i < 6; ++i) {
            int hh = h0 + i - 1;
            if ((unsigned)hh < 64u) {
                const float* p = xn + (size_t)(c * 32 + scg * 8) * 4096 + hh * 64 + sw;
                #pragma unroll
                for (int e = 0; e < 8; ++e) xr[i][e] = p[(size_t)e * 4096];
            } else {
                #pragma unroll
                for (int e = 0; e < 8; ++e) xr[i][e] = 0.f;
            }
        }
    };
    auto write_chunk = [&](int b) {
        #pragma unroll
        for (int i = 0; i < 6; ++i) {
            uint4v v;
            #pragma unroll
            for (int e = 0; e < 4; ++e) {
                __hip_bfloat162 pk = __float22bfloat162_rn(
                    make_float2(xr[i][2 * e], xr[i][2 * e + 1]));
                union { __hip_bfloat162 h; unsigned u; } cv; cv.h = pk;
                v[e] = cv.u;
            }
            *(uint4v*)&lds[b * 1536 + i * 256 + scg * 64 + sw] = v;
        }
    };

    floatx16 acc[2][4];   // [o-tile][t = hr*2 + wh]
    #pragma unroll
    for (int ot = 0; ot < 2; ++ot)
        #pragma unroll
        for (int t = 0; t < 4; ++t)
            #pragma unroll
            for (int e = 0; e < 16; ++e) acc[ot][t][e] = 0.f;

    const int laneoff = lh * 1024 + l31 * 16;              // lane part of B addr (bytes)
    const char* zcell = (const char*)&lds[2 * 1536];

    load_chunk(0);
    write_chunk(0);
    __syncthreads();

    for (int c = 0; c < 8; ++c) {
        const int cb = c & 1;
        if (c < 7) load_chunk(c + 1);                      // regs; lands during MFMA

        const unsigned short* wbase = wb + (size_t)(owave + l31) * 256 + c * 32;
        const char* bufb = (const char*)&lds[cb * 1536];

        #pragma unroll
        for (int ks = 0; ks < 2; ++ks) {
            short8 a[2][KT];
            #pragma unroll
            for (int k = 0; k < KT; ++k)
                #pragma unroll
                for (int ot = 0; ot < 2; ++ot)
                    a[ot][k] = *(const short8*)(wbase + (size_t)k * 65536 + ot * 8192 + ks * 16 + lh * 8);

            // taps (dy,dx): k0=(1,1) k1=(0,1) k2=(1,0) k3=(1,2) k4=(2,1)
            #pragma unroll
            for (int k = 0; k < KT; ++k) {
                const int dy = (k == 1) ? 0 : (k == 4) ? 2 : 1;
                const int dx = (k == 2) ? 0 : (k == 3) ? 2 : 1;
                #pragma unroll
                for (int t = 0; t < 4; ++t) {
                    const int hr = t >> 1, wh = t & 1;
                    const int r  = rowbase + hr + dy;
                    const int wl = wh * 32 + l31 + dx - 1;
                    const char* bp = ((unsigned)wl < 64u)
                        ? bufb + (r * 4096 + ks * 2048 + (wh * 32 + dx - 1) * 16) + laneoff
                        : zcell;
                    const short8 bfrag = *(const short8*)bp;
                    acc[0][t] = __builtin_amdgcn_mfma_f32_32x32x16_bf16(a[0][k], bfrag, acc[0][t], 0, 0, 0);
                    acc[1][t] = __builtin_amdgcn_mfma_f32_32x32x16_bf16(a[1][k], bfrag, acc[1][t], 0, 0, 0);
                }
            }
        }

        if (c < 7) write_chunk(cb ^ 1);    // buffer cb^1: last read ended chunk c-1
        __syncthreads();
    }

    // epilogue: C/D: col(px) = l31, row(o-off) = (reg&3) + 8*(reg>>2) + 4*lh
    #pragma unroll
    for (int ot = 0; ot < 2; ++ot) {
        #pragma unroll
        for (int t = 0; t < 4; ++t) {
            const int hr = t >> 1, wh = t & 1;
            const int h = h0 + rowbase + hr;
            #pragma unroll
            for (int reg = 0; reg < 16; ++reg) {
                int o = owave + ot * 32 + (reg & 3) + 8 * (reg >> 2) + 4 * lh;
                out[(((size_t)n * CO + o) * 64 + h) * 64 + wh * 32 + l31] = acc[ot][t][reg];
            }
        }
    }
}

extern "C" void kernel_launch(void* const* d_in, const int* in_sizes, int n_in,
                              void* d_out, int out_size, void* d_ws, size_t ws_size,
                              hipStream_t stream) {
    const float* x = (const float*)d_in[0];
    const float* w = (const float*)d_in[1];
    float* out = (float*)d_out;

    unsigned short* wb = (unsigned short*)d_ws;    // 640 KB, the only workspace

    wtrans_kernel<<<dim3((KT * CO * CI + 255) / 256), dim3(256), 0, stream>>>(w, wb);
    conv_mfma<<<dim3(N_ * 16 * 2), dim3(256), 0, stream>>>(x, wb, out);
}